// Round 12
// baseline (166.995 us; speedup 1.0000x reference)
//
#include <hip/hip_runtime.h>

#define N_NODES 100000
#define N_EDGES 1200000
#define D 64
#define KP 68                           // padded LDS row for W^T
#define TN 64                           // nodes per gemm block tile (r4 best)
#define CAP 48                          // per-node bucket capacity (in-deg ~ Poisson(12))
#define Q15 32767.0f
#define INVQ15 (1.0f / 32767.0f)
#define BW 512                          // coarse bucket width (nodes)
#define BSH 9
#define NBKT ((N_NODES + BW - 1) / BW)  // 196
#define CAPB 8192                       // slots per coarse bucket (mean 6144, 26-sigma margin)
#define N4 (N_EDGES / 4)                // 300000
#define NB_COARSE ((N4 + 511) / 512)    // 586 coarse blocks (2048 edges each)
#define NB_GEMM ((N_NODES + TN - 1) / TN) // 1563 gemm blocks
#define NB_AGG 2048                     // grid-stride: 8 blocks/CU, 32 waves/CU resident
#define NJOBS_AGG (N_NODES / 8)         // 12500 jobs of 8 nodes

__device__ __forceinline__ unsigned short f2bf(float f) {   // RNE fp32 -> bf16
    unsigned u = __float_as_uint(f);
    return (unsigned short)((u + 0x7FFFu + ((u >> 16) & 1u)) >> 16);
}
__device__ __forceinline__ float bf2f(unsigned short h) {
    return __uint_as_float((unsigned)h << 16);
}

// ============ Fused Phase A: coarse binning blocks + GEMM blocks ============
// Coarse role sorts its 2048 records by bucket in LDS (aliasing the GEMM's wt
// buffer) and writes each bucket's run contiguously -> coalesced full-line
// stores. rec.y carries the bucket id in bits 24-31 (ignored by k_bin's masks).
__global__ __launch_bounds__(256) void k_pre(const int4* __restrict__ row4,
                                             const int4* __restrict__ col4,
                                             const float4* __restrict__ ew4,
                                             int* __restrict__ gcur,
                                             int2* __restrict__ coarse,
                                             const float* __restrict__ x,
                                             const float* __restrict__ W,
                                             unsigned short* __restrict__ hb,
                                             int n4, int n_nodes) {
    __shared__ int lcnt[NBKT];
    __shared__ int lbase[NBKT];
    __shared__ float wt[D * KP];     // gemm: W^T | coarse: sorted[2048] + bofs[196]
    int t = threadIdx.x;

    if (blockIdx.x < NB_COARSE) {
        // ---------------- coarse binning role ----------------
        int2* sorted = (int2*)wt;                        // 16384 B
        int*  bofs   = (int*)((char*)wt + 16384);        // 784 B (fits in 17408)
        for (int i = t; i < NBKT; i += 256) lcnt[i] = 0;
        __syncthreads();

        int bkt[8]; int slot[8]; int2 rec[8];
        #pragma unroll
        for (int k = 0; k < 8; k++) bkt[k] = -1;

        #pragma unroll
        for (int r = 0; r < 2; r++) {
            int q = blockIdx.x * 512 + r * 256 + t;
            if (q < n4) {
                int4 rr = row4[q]; int4 cc = col4[q]; float4 ww = ew4[q];
                int j = r * 4;
                int c, bk;
                c = cc.x; bk = c >> BSH; bkt[j+0] = bk;
                rec[j+0] = make_int2(rr.x, (bk << 24) | ((c & (BW-1)) << 15) | (int)(ww.x * Q15 + 0.5f));
                slot[j+0] = atomicAdd(&lcnt[bk], 1);
                c = cc.y; bk = c >> BSH; bkt[j+1] = bk;
                rec[j+1] = make_int2(rr.y, (bk << 24) | ((c & (BW-1)) << 15) | (int)(ww.y * Q15 + 0.5f));
                slot[j+1] = atomicAdd(&lcnt[bk], 1);
                c = cc.z; bk = c >> BSH; bkt[j+2] = bk;
                rec[j+2] = make_int2(rr.z, (bk << 24) | ((c & (BW-1)) << 15) | (int)(ww.z * Q15 + 0.5f));
                slot[j+2] = atomicAdd(&lcnt[bk], 1);
                c = cc.w; bk = c >> BSH; bkt[j+3] = bk;
                rec[j+3] = make_int2(rr.w, (bk << 24) | ((c & (BW-1)) << 15) | (int)(ww.w * Q15 + 0.5f));
                slot[j+3] = atomicAdd(&lcnt[bk], 1);
            }
        }
        __syncthreads();
        // global base alloc + inclusive Hillis-Steele scan over lcnt -> bofs
        for (int i = t; i < NBKT; i += 256) {
            int c = lcnt[i];
            lbase[i] = c ? atomicAdd(&gcur[i], c) : 0;
            bofs[i] = c;
        }
        __syncthreads();
        for (int d = 1; d < NBKT; d <<= 1) {
            int v = 0;
            if (t < NBKT && t >= d) v = bofs[t - d];
            __syncthreads();
            if (t < NBKT && t >= d) bofs[t] += v;
            __syncthreads();
        }
        if (t < NBKT) bofs[t] -= lcnt[t];    // exclusive prefix
        __syncthreads();

        // place records into bucket-sorted LDS order
        #pragma unroll
        for (int k = 0; k < 8; k++)
            if (bkt[k] >= 0) sorted[bofs[bkt[k]] + slot[k]] = rec[k];
        __syncthreads();

        // linear stream-out: contiguous run per bucket -> coalesced
        int m = bofs[NBKT - 1] + lcnt[NBKT - 1];
        for (int i = t; i < m; i += 256) {
            int2 r = sorted[i];
            int bk = ((unsigned)r.y) >> 24;
            int pos = lbase[bk] + (i - bofs[bk]);
            if (pos < CAPB) coarse[(size_t)bk * CAPB + pos] = r;
        }
    } else {
        // ---------------- GEMM role (r4 exact) ----------------
        int base = (blockIdx.x - NB_COARSE) * TN;
        #pragma unroll
        for (int c = 0; c < 16; c++) {
            int idx = t + c * 256;       // idx = f*64 + k
            wt[(idx & 63) * KP + (idx >> 6)] = W[idx];
        }
        __syncthreads();

        int tx = t & 15, ty = t >> 4;
        int f0 = tx * 4, n0 = base + ty * 4;
        const float* xr0 = x + (size_t)min(n0 + 0, n_nodes - 1) * D;
        const float* xr1 = x + (size_t)min(n0 + 1, n_nodes - 1) * D;
        const float* xr2 = x + (size_t)min(n0 + 2, n_nodes - 1) * D;
        const float* xr3 = x + (size_t)min(n0 + 3, n_nodes - 1) * D;

        float acc[4][4] = {};
        #pragma unroll 4
        for (int k = 0; k < D; k += 4) {
            float a[4][4], wv[4][4];
            *(float4*)a[0] = *(const float4*)&xr0[k];
            *(float4*)a[1] = *(const float4*)&xr1[k];
            *(float4*)a[2] = *(const float4*)&xr2[k];
            *(float4*)a[3] = *(const float4*)&xr3[k];
            #pragma unroll
            for (int kk = 0; kk < 4; kk++)
                *(float4*)wv[kk] = *(const float4*)&wt[(k + kk) * KP + f0];
            #pragma unroll
            for (int kk = 0; kk < 4; kk++)
                #pragma unroll
                for (int j = 0; j < 4; j++)
                    #pragma unroll
                    for (int ff = 0; ff < 4; ff++)
                        acc[j][ff] = fmaf(a[j][kk], wv[kk][ff], acc[j][ff]);
        }
        #pragma unroll
        for (int j = 0; j < 4; j++) {
            int n = n0 + j;
            if (n < n_nodes) {
                unsigned short h0 = f2bf(acc[j][0]);
                unsigned short h1 = f2bf(acc[j][1]);
                unsigned short h2 = f2bf(acc[j][2]);
                unsigned short h3 = f2bf(acc[j][3]);
                uint2 pk;
                pk.x = (unsigned)h0 | ((unsigned)h1 << 16);
                pk.y = (unsigned)h2 | ((unsigned)h3 << 16);
                *(uint2*)&hb[(size_t)n * D + f0] = pk;
            }
        }
    }
}

// ===== Phase B: slot-alloc scatter + deg accumulate -> cnt, dis, em (r4 exact) =====
__global__ __launch_bounds__(1024) void k_bin(const int* __restrict__ gcur,
                                              const int2* __restrict__ coarse,
                                              int* __restrict__ cnt,
                                              float* __restrict__ dis,
                                              unsigned int* __restrict__ em, int n_nodes) {
    __shared__ int   cur512[BW];
    __shared__ float d512[BW];
    int b = blockIdx.x, t = threadIdx.x;
    int total = min(gcur[b], CAPB);
    int nbase = b * BW;
    int bw = min(BW, n_nodes - nbase);
    for (int i = t; i < BW; i += 1024) { cur512[i] = 0; d512[i] = 0.f; }
    __syncthreads();
    const int2* src = &coarse[(size_t)b * CAPB];
    for (int i = t; i < total; i += 1024) {
        int2 r = src[i];
        int cl = (r.y >> 15) & (BW - 1);
        float w = (float)(r.y & 0x7FFF) * INVQ15;
        int s = atomicAdd(&cur512[cl], 1);
        atomicAdd(&d512[cl], w);
        if (s < CAP)
            em[(size_t)(nbase + cl) * CAP + s] = ((unsigned)r.x << 15) | (unsigned)(r.y & 0x7FFF);
    }
    __syncthreads();
    for (int i = t; i < bw; i += 1024) {
        cnt[nbase + i] = cur512[i];
        dis[nbase + i] = rsqrtf(1.0f + d512[i]);
    }
}

// ============ aggregate — GRID-STRIDE at 2048 blocks ============
// 12500 tiny blocks made k_agg dispatch-rate-bound (Occupancy 60% at VGPR 28 /
// LDS 0, insensitive to all instruction changes). 2048 blocks x 4 waves = 32
// waves/CU resident; each block walks ~6 jobs of 8 nodes. Per-wave 2-node
// machinery unchanged (best measured).
#define AGG_STEP(rec, accv)                                                          \
    {                                                                                \
        float hh = bf2f(hsb[(size_t)((rec) >> 15) * D + l]);                         \
        accv = fmaf((float)((rec) & 0x7FFFu) * INVQ15 * dis[(rec) >> 15], hh, accv); \
    }
__global__ __launch_bounds__(256) void k_agg_cap(const int* __restrict__ cnt,
                                                 const unsigned int* __restrict__ em,
                                                 const unsigned short* __restrict__ hsb,
                                                 const float* __restrict__ dis,
                                                 const float* __restrict__ b,
                                                 float* __restrict__ out, int n_nodes) {
    int w = threadIdx.x >> 6, l = threadIdx.x & 63;
    float bl = b[l];
    for (int job = blockIdx.x; job < NJOBS_AGG; job += NB_AGG) {
        int n0 = job * 8 + w * 2;
        int n1 = n0 + 1;
        int c0 = min(cnt[n0], CAP);
        int c1 = min(cnt[n1], CAP);
        int recs0 = (int)em[(size_t)n0 * CAP + min(l, max(c0 - 1, 0))];
        int recs1 = (int)em[(size_t)n1 * CAP + min(l, max(c1 - 1, 0))];
        float ds0 = dis[n0], ds1 = dis[n1];
        float acc0 = ds0 * bf2f(hsb[(size_t)n0 * D + l]);
        float acc1 = ds1 * bf2f(hsb[(size_t)n1 * D + l]);

        int i0 = 0, i1 = 0;
        while (i0 + 4 <= c0 && i1 + 4 <= c1) {
            unsigned a0 = (unsigned)__shfl(recs0, i0 + 0);
            unsigned a1 = (unsigned)__shfl(recs0, i0 + 1);
            unsigned a2 = (unsigned)__shfl(recs0, i0 + 2);
            unsigned a3 = (unsigned)__shfl(recs0, i0 + 3);
            unsigned b0 = (unsigned)__shfl(recs1, i1 + 0);
            unsigned b1 = (unsigned)__shfl(recs1, i1 + 1);
            unsigned b2 = (unsigned)__shfl(recs1, i1 + 2);
            unsigned b3 = (unsigned)__shfl(recs1, i1 + 3);
            float ha0 = bf2f(hsb[(size_t)(a0 >> 15) * D + l]);
            float ha1 = bf2f(hsb[(size_t)(a1 >> 15) * D + l]);
            float ha2 = bf2f(hsb[(size_t)(a2 >> 15) * D + l]);
            float ha3 = bf2f(hsb[(size_t)(a3 >> 15) * D + l]);
            float hb0 = bf2f(hsb[(size_t)(b0 >> 15) * D + l]);
            float hb1 = bf2f(hsb[(size_t)(b1 >> 15) * D + l]);
            float hb2 = bf2f(hsb[(size_t)(b2 >> 15) * D + l]);
            float hb3 = bf2f(hsb[(size_t)(b3 >> 15) * D + l]);
            float wa0 = (float)(a0 & 0x7FFFu) * INVQ15 * dis[a0 >> 15];
            float wa1 = (float)(a1 & 0x7FFFu) * INVQ15 * dis[a1 >> 15];
            float wa2 = (float)(a2 & 0x7FFFu) * INVQ15 * dis[a2 >> 15];
            float wa3 = (float)(a3 & 0x7FFFu) * INVQ15 * dis[a3 >> 15];
            float wb0 = (float)(b0 & 0x7FFFu) * INVQ15 * dis[b0 >> 15];
            float wb1 = (float)(b1 & 0x7FFFu) * INVQ15 * dis[b1 >> 15];
            float wb2 = (float)(b2 & 0x7FFFu) * INVQ15 * dis[b2 >> 15];
            float wb3 = (float)(b3 & 0x7FFFu) * INVQ15 * dis[b3 >> 15];
            acc0 = fmaf(wa0, ha0, acc0);
            acc0 = fmaf(wa1, ha1, acc0);
            acc0 = fmaf(wa2, ha2, acc0);
            acc0 = fmaf(wa3, ha3, acc0);
            acc1 = fmaf(wb0, hb0, acc1);
            acc1 = fmaf(wb1, hb1, acc1);
            acc1 = fmaf(wb2, hb2, acc1);
            acc1 = fmaf(wb3, hb3, acc1);
            i0 += 4; i1 += 4;
        }
        for (; i0 + 4 <= c0; i0 += 4) {
            unsigned a0 = (unsigned)__shfl(recs0, i0 + 0);
            unsigned a1 = (unsigned)__shfl(recs0, i0 + 1);
            unsigned a2 = (unsigned)__shfl(recs0, i0 + 2);
            unsigned a3 = (unsigned)__shfl(recs0, i0 + 3);
            float ha0 = bf2f(hsb[(size_t)(a0 >> 15) * D + l]);
            float ha1 = bf2f(hsb[(size_t)(a1 >> 15) * D + l]);
            float ha2 = bf2f(hsb[(size_t)(a2 >> 15) * D + l]);
            float ha3 = bf2f(hsb[(size_t)(a3 >> 15) * D + l]);
            acc0 = fmaf((float)(a0 & 0x7FFFu) * INVQ15 * dis[a0 >> 15], ha0, acc0);
            acc0 = fmaf((float)(a1 & 0x7FFFu) * INVQ15 * dis[a1 >> 15], ha1, acc0);
            acc0 = fmaf((float)(a2 & 0x7FFFu) * INVQ15 * dis[a2 >> 15], ha2, acc0);
            acc0 = fmaf((float)(a3 & 0x7FFFu) * INVQ15 * dis[a3 >> 15], ha3, acc0);
        }
        for (; i0 < c0; i0++) {
            unsigned a = (unsigned)__shfl(recs0, i0);
            AGG_STEP(a, acc0);
        }
        for (; i1 + 4 <= c1; i1 += 4) {
            unsigned b0 = (unsigned)__shfl(recs1, i1 + 0);
            unsigned b1 = (unsigned)__shfl(recs1, i1 + 1);
            unsigned b2 = (unsigned)__shfl(recs1, i1 + 2);
            unsigned b3 = (unsigned)__shfl(recs1, i1 + 3);
            float hb0 = bf2f(hsb[(size_t)(b0 >> 15) * D + l]);
            float hb1 = bf2f(hsb[(size_t)(b1 >> 15) * D + l]);
            float hb2 = bf2f(hsb[(size_t)(b2 >> 15) * D + l]);
            float hb3 = bf2f(hsb[(size_t)(b3 >> 15) * D + l]);
            acc1 = fmaf((float)(b0 & 0x7FFFu) * INVQ15 * dis[b0 >> 15], hb0, acc1);
            acc1 = fmaf((float)(b1 & 0x7FFFu) * INVQ15 * dis[b1 >> 15], hb1, acc1);
            acc1 = fmaf((float)(b2 & 0x7FFFu) * INVQ15 * dis[b2 >> 15], hb2, acc1);
            acc1 = fmaf((float)(b3 & 0x7FFFu) * INVQ15 * dis[b3 >> 15], hb3, acc1);
        }
        for (; i1 < c1; i1++) {
            unsigned bb = (unsigned)__shfl(recs1, i1);
            AGG_STEP(bb, acc1);
        }

        float v0 = fmaf(ds0, acc0, bl);
        float v1 = fmaf(ds1, acc1, bl);
        out[(size_t)n0 * D + l] = v0 > 0.f ? v0 : 0.f;
        out[(size_t)n1 * D + l] = v1 > 0.f ? v1 : 0.f;
    }
}

extern "C" void kernel_launch(void* const* d_in, const int* in_sizes, int n_in,
                              void* d_out, int out_size, void* d_ws, size_t ws_size,
                              hipStream_t stream) {
    const float* x   = (const float*)d_in[0];
    const int*   ei  = (const int*)d_in[1];      // [2, E]: row = ei, col = ei + E
    const float* ew  = (const float*)d_in[2];
    const float* W   = (const float*)d_in[3];
    const float* b   = (const float*)d_in[4];
    float* out = (float*)d_out;

    const int* row = ei;
    const int* col = ei + N_EDGES;

    // ---- workspace carve-up (~46 MB; ws is ~268 MB) ----
    char* p = (char*)d_ws;
    auto carve = [&](size_t bytes) { char* q = p; p += (bytes + 255) & ~(size_t)255; return q; };
    float*          dis    = (float*)carve(N_NODES * sizeof(float));
    unsigned short* hb     = (unsigned short*)carve((size_t)N_NODES * D * sizeof(unsigned short));
    int*            cnt    = (int*)  carve(N_NODES * sizeof(int));
    unsigned int*   em     = (unsigned int*)carve((size_t)N_NODES * CAP * sizeof(unsigned int));
    int*            gcur   = (int*)  carve(NBKT * sizeof(int));
    int2*           coarse = (int2*) carve((size_t)NBKT * CAPB * sizeof(int2));

    hipMemsetAsync(gcur, 0, NBKT * sizeof(int), stream);

    k_pre<<<NB_COARSE + NB_GEMM, 256, 0, stream>>>(
        (const int4*)row, (const int4*)col, (const float4*)ew, gcur, coarse,
        x, W, hb, N4, N_NODES);
    k_bin<<<NBKT, 1024, 0, stream>>>(gcur, coarse, cnt, dis, em, N_NODES);
    k_agg_cap<<<NB_AGG, 256, 0, stream>>>(cnt, em, hb, dis, b, out, N_NODES);
}

// Round 13
// 165.045 us; speedup vs baseline: 1.0118x; 1.0118x over previous
//
#include <hip/hip_runtime.h>

#define N_NODES 100000
#define N_EDGES 1200000
#define D 64
#define KP 68                           // padded LDS row for W^T
#define TN 64                           // nodes per gemm block tile (r4 best)
#define CAP 48                          // per-node bucket capacity (in-deg ~ Poisson(12))
#define Q15 32767.0f
#define INVQ15 (1.0f / 32767.0f)
#define BW 512                          // coarse bucket width (nodes)
#define BSH 9
#define NBKT ((N_NODES + BW - 1) / BW)  // 196
#define CAPB 8192                       // slots per coarse bucket (mean 6144, 26-sigma margin)
#define N4 (N_EDGES / 4)                // 300000
#define NB_COARSE ((N4 + 511) / 512)    // 586 coarse blocks (2048 edges each)
#define NB_GEMM ((N_NODES + TN - 1) / TN) // 1563 gemm blocks

__device__ __forceinline__ unsigned short f2bf(float f) {   // RNE fp32 -> bf16
    unsigned u = __float_as_uint(f);
    return (unsigned short)((u + 0x7FFFu + ((u >> 16) & 1u)) >> 16);
}
__device__ __forceinline__ float bf2f(unsigned short h) {
    return __uint_as_float((unsigned)h << 16);
}

// ============ Fused Phase A: coarse binning blocks + GEMM blocks ============
// Coarse role sorts its 2048 records by bucket in LDS (aliasing the GEMM's wt
// buffer) and writes each bucket's run contiguously -> coalesced full-line
// stores. rec.y carries the bucket id in bits 24-31 (ignored by k_bin's masks).
// [r11 best-measured: 164.6 us total]
__global__ __launch_bounds__(256) void k_pre(const int4* __restrict__ row4,
                                             const int4* __restrict__ col4,
                                             const float4* __restrict__ ew4,
                                             int* __restrict__ gcur,
                                             int2* __restrict__ coarse,
                                             const float* __restrict__ x,
                                             const float* __restrict__ W,
                                             unsigned short* __restrict__ hb,
                                             int n4, int n_nodes) {
    __shared__ int lcnt[NBKT];
    __shared__ int lbase[NBKT];
    __shared__ float wt[D * KP];     // gemm: W^T | coarse: sorted[2048] + bofs[196]
    int t = threadIdx.x;

    if (blockIdx.x < NB_COARSE) {
        // ---------------- coarse binning role ----------------
        int2* sorted = (int2*)wt;                        // 16384 B
        int*  bofs   = (int*)((char*)wt + 16384);        // 784 B (fits in 17408)
        for (int i = t; i < NBKT; i += 256) lcnt[i] = 0;
        __syncthreads();

        int bkt[8]; int slot[8]; int2 rec[8];
        #pragma unroll
        for (int k = 0; k < 8; k++) bkt[k] = -1;

        #pragma unroll
        for (int r = 0; r < 2; r++) {
            int q = blockIdx.x * 512 + r * 256 + t;
            if (q < n4) {
                int4 rr = row4[q]; int4 cc = col4[q]; float4 ww = ew4[q];
                int j = r * 4;
                int c, bk;
                c = cc.x; bk = c >> BSH; bkt[j+0] = bk;
                rec[j+0] = make_int2(rr.x, (bk << 24) | ((c & (BW-1)) << 15) | (int)(ww.x * Q15 + 0.5f));
                slot[j+0] = atomicAdd(&lcnt[bk], 1);
                c = cc.y; bk = c >> BSH; bkt[j+1] = bk;
                rec[j+1] = make_int2(rr.y, (bk << 24) | ((c & (BW-1)) << 15) | (int)(ww.y * Q15 + 0.5f));
                slot[j+1] = atomicAdd(&lcnt[bk], 1);
                c = cc.z; bk = c >> BSH; bkt[j+2] = bk;
                rec[j+2] = make_int2(rr.z, (bk << 24) | ((c & (BW-1)) << 15) | (int)(ww.z * Q15 + 0.5f));
                slot[j+2] = atomicAdd(&lcnt[bk], 1);
                c = cc.w; bk = c >> BSH; bkt[j+3] = bk;
                rec[j+3] = make_int2(rr.w, (bk << 24) | ((c & (BW-1)) << 15) | (int)(ww.w * Q15 + 0.5f));
                slot[j+3] = atomicAdd(&lcnt[bk], 1);
            }
        }
        __syncthreads();
        // global base alloc + inclusive Hillis-Steele scan over lcnt -> bofs
        for (int i = t; i < NBKT; i += 256) {
            int c = lcnt[i];
            lbase[i] = c ? atomicAdd(&gcur[i], c) : 0;
            bofs[i] = c;
        }
        __syncthreads();
        for (int d = 1; d < NBKT; d <<= 1) {
            int v = 0;
            if (t < NBKT && t >= d) v = bofs[t - d];
            __syncthreads();
            if (t < NBKT && t >= d) bofs[t] += v;
            __syncthreads();
        }
        if (t < NBKT) bofs[t] -= lcnt[t];    // exclusive prefix
        __syncthreads();

        // place records into bucket-sorted LDS order
        #pragma unroll
        for (int k = 0; k < 8; k++)
            if (bkt[k] >= 0) sorted[bofs[bkt[k]] + slot[k]] = rec[k];
        __syncthreads();

        // linear stream-out: contiguous run per bucket -> coalesced
        int m = bofs[NBKT - 1] + lcnt[NBKT - 1];
        for (int i = t; i < m; i += 256) {
            int2 r = sorted[i];
            int bk = ((unsigned)r.y) >> 24;
            int pos = lbase[bk] + (i - bofs[bk]);
            if (pos < CAPB) coarse[(size_t)bk * CAPB + pos] = r;
        }
    } else {
        // ---------------- GEMM role (r4 exact) ----------------
        int base = (blockIdx.x - NB_COARSE) * TN;
        #pragma unroll
        for (int c = 0; c < 16; c++) {
            int idx = t + c * 256;       // idx = f*64 + k
            wt[(idx & 63) * KP + (idx >> 6)] = W[idx];
        }
        __syncthreads();

        int tx = t & 15, ty = t >> 4;
        int f0 = tx * 4, n0 = base + ty * 4;
        const float* xr0 = x + (size_t)min(n0 + 0, n_nodes - 1) * D;
        const float* xr1 = x + (size_t)min(n0 + 1, n_nodes - 1) * D;
        const float* xr2 = x + (size_t)min(n0 + 2, n_nodes - 1) * D;
        const float* xr3 = x + (size_t)min(n0 + 3, n_nodes - 1) * D;

        float acc[4][4] = {};
        #pragma unroll 4
        for (int k = 0; k < D; k += 4) {
            float a[4][4], wv[4][4];
            *(float4*)a[0] = *(const float4*)&xr0[k];
            *(float4*)a[1] = *(const float4*)&xr1[k];
            *(float4*)a[2] = *(const float4*)&xr2[k];
            *(float4*)a[3] = *(const float4*)&xr3[k];
            #pragma unroll
            for (int kk = 0; kk < 4; kk++)
                *(float4*)wv[kk] = *(const float4*)&wt[(k + kk) * KP + f0];
            #pragma unroll
            for (int kk = 0; kk < 4; kk++)
                #pragma unroll
                for (int j = 0; j < 4; j++)
                    #pragma unroll
                    for (int ff = 0; ff < 4; ff++)
                        acc[j][ff] = fmaf(a[j][kk], wv[kk][ff], acc[j][ff]);
        }
        #pragma unroll
        for (int j = 0; j < 4; j++) {
            int n = n0 + j;
            if (n < n_nodes) {
                unsigned short h0 = f2bf(acc[j][0]);
                unsigned short h1 = f2bf(acc[j][1]);
                unsigned short h2 = f2bf(acc[j][2]);
                unsigned short h3 = f2bf(acc[j][3]);
                uint2 pk;
                pk.x = (unsigned)h0 | ((unsigned)h1 << 16);
                pk.y = (unsigned)h2 | ((unsigned)h3 << 16);
                *(uint2*)&hb[(size_t)n * D + f0] = pk;
            }
        }
    }
}

// ===== Phase B: slot-alloc scatter + deg accumulate -> cnt, dis, em (r4 exact) =====
// (high bits 24-31 of r.y hold the bucket id; all masks below ignore them)
__global__ __launch_bounds__(1024) void k_bin(const int* __restrict__ gcur,
                                              const int2* __restrict__ coarse,
                                              int* __restrict__ cnt,
                                              float* __restrict__ dis,
                                              unsigned int* __restrict__ em, int n_nodes) {
    __shared__ int   cur512[BW];
    __shared__ float d512[BW];
    int b = blockIdx.x, t = threadIdx.x;
    int total = min(gcur[b], CAPB);
    int nbase = b * BW;
    int bw = min(BW, n_nodes - nbase);
    for (int i = t; i < BW; i += 1024) { cur512[i] = 0; d512[i] = 0.f; }
    __syncthreads();
    const int2* src = &coarse[(size_t)b * CAPB];
    for (int i = t; i < total; i += 1024) {
        int2 r = src[i];
        int cl = (r.y >> 15) & (BW - 1);
        float w = (float)(r.y & 0x7FFF) * INVQ15;
        int s = atomicAdd(&cur512[cl], 1);
        atomicAdd(&d512[cl], w);
        if (s < CAP)
            em[(size_t)(nbase + cl) * CAP + s] = ((unsigned)r.x << 15) | (unsigned)(r.y & 0x7FFF);
    }
    __syncthreads();
    for (int i = t; i < bw; i += 1024) {
        cnt[nbase + i] = cur512[i];
        dis[nbase + i] = rsqrtf(1.0f + d512[i]);
    }
}

// ============ aggregate (r4/r11 exact — best measured; 42.9us = gather-BW floor) ============
// Floor arithmetic: 1.2M random 128B hb-row gathers = 153.6 MB via L3 at the
// measured ~3.6 TB/s random-gather throughput = 42.7us. Invariant across 7
// structural variants (MLP depth, inst count, residency) -> hardware-bound.
#define AGG_STEP(rec, accv)                                                          \
    {                                                                                \
        float hh = bf2f(hsb[(size_t)((rec) >> 15) * D + l]);                         \
        accv = fmaf((float)((rec) & 0x7FFFu) * INVQ15 * dis[(rec) >> 15], hh, accv); \
    }
__global__ __launch_bounds__(256) void k_agg_cap(const int* __restrict__ cnt,
                                                 const unsigned int* __restrict__ em,
                                                 const unsigned short* __restrict__ hsb,
                                                 const float* __restrict__ dis,
                                                 const float* __restrict__ b,
                                                 float* __restrict__ out, int n_nodes) {
    int w = threadIdx.x >> 6, l = threadIdx.x & 63;
    int n0 = blockIdx.x * 8 + w * 2;
    int n1 = n0 + 1;
    int c0 = min(cnt[n0], CAP);
    int c1 = min(cnt[n1], CAP);
    int recs0 = (int)em[(size_t)n0 * CAP + min(l, max(c0 - 1, 0))];
    int recs1 = (int)em[(size_t)n1 * CAP + min(l, max(c1 - 1, 0))];
    float ds0 = dis[n0], ds1 = dis[n1];
    float acc0 = ds0 * bf2f(hsb[(size_t)n0 * D + l]);
    float acc1 = ds1 * bf2f(hsb[(size_t)n1 * D + l]);

    int i0 = 0, i1 = 0;
    while (i0 + 4 <= c0 && i1 + 4 <= c1) {
        unsigned a0 = (unsigned)__shfl(recs0, i0 + 0);
        unsigned a1 = (unsigned)__shfl(recs0, i0 + 1);
        unsigned a2 = (unsigned)__shfl(recs0, i0 + 2);
        unsigned a3 = (unsigned)__shfl(recs0, i0 + 3);
        unsigned b0 = (unsigned)__shfl(recs1, i1 + 0);
        unsigned b1 = (unsigned)__shfl(recs1, i1 + 1);
        unsigned b2 = (unsigned)__shfl(recs1, i1 + 2);
        unsigned b3 = (unsigned)__shfl(recs1, i1 + 3);
        float ha0 = bf2f(hsb[(size_t)(a0 >> 15) * D + l]);
        float ha1 = bf2f(hsb[(size_t)(a1 >> 15) * D + l]);
        float ha2 = bf2f(hsb[(size_t)(a2 >> 15) * D + l]);
        float ha3 = bf2f(hsb[(size_t)(a3 >> 15) * D + l]);
        float hb0 = bf2f(hsb[(size_t)(b0 >> 15) * D + l]);
        float hb1 = bf2f(hsb[(size_t)(b1 >> 15) * D + l]);
        float hb2 = bf2f(hsb[(size_t)(b2 >> 15) * D + l]);
        float hb3 = bf2f(hsb[(size_t)(b3 >> 15) * D + l]);
        float wa0 = (float)(a0 & 0x7FFFu) * INVQ15 * dis[a0 >> 15];
        float wa1 = (float)(a1 & 0x7FFFu) * INVQ15 * dis[a1 >> 15];
        float wa2 = (float)(a2 & 0x7FFFu) * INVQ15 * dis[a2 >> 15];
        float wa3 = (float)(a3 & 0x7FFFu) * INVQ15 * dis[a3 >> 15];
        float wb0 = (float)(b0 & 0x7FFFu) * INVQ15 * dis[b0 >> 15];
        float wb1 = (float)(b1 & 0x7FFFu) * INVQ15 * dis[b1 >> 15];
        float wb2 = (float)(b2 & 0x7FFFu) * INVQ15 * dis[b2 >> 15];
        float wb3 = (float)(b3 & 0x7FFFu) * INVQ15 * dis[b3 >> 15];
        acc0 = fmaf(wa0, ha0, acc0);
        acc0 = fmaf(wa1, ha1, acc0);
        acc0 = fmaf(wa2, ha2, acc0);
        acc0 = fmaf(wa3, ha3, acc0);
        acc1 = fmaf(wb0, hb0, acc1);
        acc1 = fmaf(wb1, hb1, acc1);
        acc1 = fmaf(wb2, hb2, acc1);
        acc1 = fmaf(wb3, hb3, acc1);
        i0 += 4; i1 += 4;
    }
    for (; i0 + 4 <= c0; i0 += 4) {
        unsigned a0 = (unsigned)__shfl(recs0, i0 + 0);
        unsigned a1 = (unsigned)__shfl(recs0, i0 + 1);
        unsigned a2 = (unsigned)__shfl(recs0, i0 + 2);
        unsigned a3 = (unsigned)__shfl(recs0, i0 + 3);
        float ha0 = bf2f(hsb[(size_t)(a0 >> 15) * D + l]);
        float ha1 = bf2f(hsb[(size_t)(a1 >> 15) * D + l]);
        float ha2 = bf2f(hsb[(size_t)(a2 >> 15) * D + l]);
        float ha3 = bf2f(hsb[(size_t)(a3 >> 15) * D + l]);
        acc0 = fmaf((float)(a0 & 0x7FFFu) * INVQ15 * dis[a0 >> 15], ha0, acc0);
        acc0 = fmaf((float)(a1 & 0x7FFFu) * INVQ15 * dis[a1 >> 15], ha1, acc0);
        acc0 = fmaf((float)(a2 & 0x7FFFu) * INVQ15 * dis[a2 >> 15], ha2, acc0);
        acc0 = fmaf((float)(a3 & 0x7FFFu) * INVQ15 * dis[a3 >> 15], ha3, acc0);
    }
    for (; i0 < c0; i0++) {
        unsigned a = (unsigned)__shfl(recs0, i0);
        AGG_STEP(a, acc0);
    }
    for (; i1 + 4 <= c1; i1 += 4) {
        unsigned b0 = (unsigned)__shfl(recs1, i1 + 0);
        unsigned b1 = (unsigned)__shfl(recs1, i1 + 1);
        unsigned b2 = (unsigned)__shfl(recs1, i1 + 2);
        unsigned b3 = (unsigned)__shfl(recs1, i1 + 3);
        float hb0 = bf2f(hsb[(size_t)(b0 >> 15) * D + l]);
        float hb1 = bf2f(hsb[(size_t)(b1 >> 15) * D + l]);
        float hb2 = bf2f(hsb[(size_t)(b2 >> 15) * D + l]);
        float hb3 = bf2f(hsb[(size_t)(b3 >> 15) * D + l]);
        acc1 = fmaf((float)(b0 & 0x7FFFu) * INVQ15 * dis[b0 >> 15], hb0, acc1);
        acc1 = fmaf((float)(b1 & 0x7FFFu) * INVQ15 * dis[b1 >> 15], hb1, acc1);
        acc1 = fmaf((float)(b2 & 0x7FFFu) * INVQ15 * dis[b2 >> 15], hb2, acc1);
        acc1 = fmaf((float)(b3 & 0x7FFFu) * INVQ15 * dis[b3 >> 15], hb3, acc1);
    }
    for (; i1 < c1; i1++) {
        unsigned bb = (unsigned)__shfl(recs1, i1);
        AGG_STEP(bb, acc1);
    }

    float bl = b[l];
    float v0 = fmaf(ds0, acc0, bl);
    float v1 = fmaf(ds1, acc1, bl);
    out[(size_t)n0 * D + l] = v0 > 0.f ? v0 : 0.f;
    out[(size_t)n1 * D + l] = v1 > 0.f ? v1 : 0.f;
}

extern "C" void kernel_launch(void* const* d_in, const int* in_sizes, int n_in,
                              void* d_out, int out_size, void* d_ws, size_t ws_size,
                              hipStream_t stream) {
    const float* x   = (const float*)d_in[0];
    const int*   ei  = (const int*)d_in[1];      // [2, E]: row = ei, col = ei + E
    const float* ew  = (const float*)d_in[2];
    const float* W   = (const float*)d_in[3];
    const float* b   = (const float*)d_in[4];
    float* out = (float*)d_out;

    const int* row = ei;
    const int* col = ei + N_EDGES;

    // ---- workspace carve-up (~46 MB; ws is ~268 MB) ----
    char* p = (char*)d_ws;
    auto carve = [&](size_t bytes) { char* q = p; p += (bytes + 255) & ~(size_t)255; return q; };
    float*          dis    = (float*)carve(N_NODES * sizeof(float));
    unsigned short* hb     = (unsigned short*)carve((size_t)N_NODES * D * sizeof(unsigned short));
    int*            cnt    = (int*)  carve(N_NODES * sizeof(int));
    unsigned int*   em     = (unsigned int*)carve((size_t)N_NODES * CAP * sizeof(unsigned int));
    int*            gcur   = (int*)  carve(NBKT * sizeof(int));
    int2*           coarse = (int2*) carve((size_t)NBKT * CAPB * sizeof(int2));

    hipMemsetAsync(gcur, 0, NBKT * sizeof(int), stream);

    k_pre<<<NB_COARSE + NB_GEMM, 256, 0, stream>>>(
        (const int4*)row, (const int4*)col, (const float4*)ew, gcur, coarse,
        x, W, hb, N4, N_NODES);
    k_bin<<<NBKT, 1024, 0, stream>>>(gcur, coarse, cnt, dis, em, N_NODES);
    k_agg_cap<<<N_NODES / 8, 256, 0, stream>>>(cnt, em, hb, dis, b, out, N_NODES);
}